// Round 8
// baseline (550.563 us; speedup 1.0000x reference)
//
#include <hip/hip_runtime.h>
#include <hip/hip_cooperative_groups.h>

namespace cg = cooperative_groups;

#define L_SEQ 2048
#define NH 8
#define DIM 64
#define SS 40
#define UU 40
#define NHD 512   // NH*DIM floats between consecutive l rows

// ======================= device bodies =======================

// m-score: wave per (b,l), all 8 heads; 8 batches of 5 K rows in VGPRs.
__device__ __forceinline__ void m_body(const float* __restrict__ Qg,
                                       const float* __restrict__ Kg,
                                       const int* __restrict__ idx,
                                       float* __restrict__ M,
                                       int bx, int tid) {
    int w = tid >> 6, lane = tid & 63;
    int b = bx & 3;                       // XCD-pinned
    int l = (bx >> 2) * 4 + w;
    int h = lane >> 3, c = lane & 7;

    const float* Qp = Qg + ((size_t)(b * L_SEQ + l) * NH + h) * DIM + c * 8;
    float4 q0 = *(const float4*)Qp;
    float4 q1 = *(const float4*)(Qp + 4);
    const float* Kbase = Kg + (size_t)b * L_SEQ * NHD + h * DIM + c * 8;
    const int* ip = idx + l * SS;

    float mx = -INFINITY, sm = 0.f;
#define DOT8(ka, kb, out) { \
    float d_ = ka.x * q0.x; \
    d_ = fmaf(ka.y, q0.y, d_); d_ = fmaf(ka.z, q0.z, d_); d_ = fmaf(ka.w, q0.w, d_); \
    d_ = fmaf(kb.x, q1.x, d_); d_ = fmaf(kb.y, q1.y, d_); \
    d_ = fmaf(kb.z, q1.z, d_); d_ = fmaf(kb.w, q1.w, d_); \
    d_ += __shfl_xor(d_, 1); d_ += __shfl_xor(d_, 2); d_ += __shfl_xor(d_, 4); \
    out = d_; }
    #pragma unroll
    for (int s = 0; s < SS; s += 5) {
        int k0 = ip[s], k1 = ip[s+1], k2 = ip[s+2], k3 = ip[s+3], k4 = ip[s+4];
        const float* r0 = Kbase + (size_t)k0 * NHD;
        const float* r1 = Kbase + (size_t)k1 * NHD;
        const float* r2 = Kbase + (size_t)k2 * NHD;
        const float* r3 = Kbase + (size_t)k3 * NHD;
        const float* r4 = Kbase + (size_t)k4 * NHD;
        float4 a0 = *(const float4*)r0, b0 = *(const float4*)(r0 + 4);
        float4 a1 = *(const float4*)r1, b1 = *(const float4*)(r1 + 4);
        float4 a2 = *(const float4*)r2, b2 = *(const float4*)(r2 + 4);
        float4 a3 = *(const float4*)r3, b3 = *(const float4*)(r3 + 4);
        float4 a4 = *(const float4*)r4, b4 = *(const float4*)(r4 + 4);
        float d0, d1, d2, d3, d4;
        DOT8(a0, b0, d0); DOT8(a1, b1, d1); DOT8(a2, b2, d2);
        DOT8(a3, b3, d3); DOT8(a4, b4, d4);
        mx = fmaxf(mx, fmaxf(fmaxf(d0, d1), fmaxf(fmaxf(d2, d3), d4)));
        sm += d0 + d1 + d2 + d3 + d4;
    }
#undef DOT8
    if (c == 0) M[((size_t)(b * NH + h)) * L_SEQ + l] = mx - sm * (1.0f / (float)L_SEQ);
}

__device__ __forceinline__ void csum8_body(const float* __restrict__ Vg,
                                           float* __restrict__ cs8,
                                           int wid, int lane) {
    int c8 = wid & 255, bh = wid >> 8;
    int b = bh >> 3, h = bh & 7;
    const float* Vp = Vg + ((size_t)(b * L_SEQ + c8 * 8) * NH + h) * DIM + lane;
    float s = 0.f;
    #pragma unroll
    for (int j = 0; j < 8; ++j) s += Vp[(size_t)j * NHD];
    cs8[((size_t)bh * 256 + c8) * 64 + lane] = s;
}

__device__ __forceinline__ void write8_body(const float* __restrict__ Vg,
                                            const float* __restrict__ cs8,
                                            float* __restrict__ out,
                                            int wid, int lane) {
    int c8 = wid & 255, bh = wid >> 8;
    int b = bh >> 3, h = bh & 7;
    float run = cs8[((size_t)bh * 256 + c8) * 64 + lane];
    size_t off = ((size_t)(b * L_SEQ + c8 * 8) * NH + h) * DIM + lane;
    const float* Vp = Vg + off;
    float* Op = out + off;
    #pragma unroll
    for (int j = 0; j < 8; ++j) {
        run += Vp[(size_t)j * NHD];
        Op[(size_t)j * NHD] = run;
    }
}

// top-40 per bh via 4-round radix select; smemf provides >=580 floats
__device__ void topk_body(const float* __restrict__ M, int* __restrict__ Mtop,
                          int bh, int tid, float* smemf) {
    unsigned* hist = (unsigned*)smemf;
    unsigned* suf  = hist + 256;
    int* eq_list   = (int*)(suf + 256);
    unsigned* scal = (unsigned*)(eq_list + 64);  // [0]=bin [1]=need [2]=cnt [3]=eqc
    const float* Mrow = M + (size_t)bh * L_SEQ;
    int base = tid * 8;

    float4 a0 = *(const float4*)(Mrow + base);
    float4 a1 = *(const float4*)(Mrow + base + 4);
    float fv[8] = {a0.x, a0.y, a0.z, a0.w, a1.x, a1.y, a1.z, a1.w};
    unsigned key[8];
    #pragma unroll
    for (int j = 0; j < 8; ++j) {
        unsigned u = __float_as_uint(fv[j]);
        key[j] = (u & 0x80000000u) ? ~u : (u | 0x80000000u);
    }
    unsigned actmask = 0xffu, thresh = 0;
    int need = UU;
    #pragma unroll
    for (int shift = 24; shift >= 0; shift -= 8) {
        hist[tid] = 0;
        __syncthreads();
        #pragma unroll
        for (int j = 0; j < 8; ++j)
            if ((actmask >> j) & 1u)
                atomicAdd(&hist[(key[j] >> shift) & 0xffu], 1u);
        __syncthreads();
        if (tid < 64) {
            int b0 = tid * 4;
            unsigned h0 = hist[b0], h1 = hist[b0 + 1], h2 = hist[b0 + 2], h3 = hist[b0 + 3];
            unsigned loc = h0 + h1 + h2 + h3;
            unsigned s = loc;
            #pragma unroll
            for (int off = 1; off < 64; off <<= 1) {
                unsigned o = __shfl_down(s, off, 64);
                if (tid + off < 64) s += o;
            }
            unsigned tail = s - loc;
            suf[b0 + 3] = tail;
            suf[b0 + 2] = tail + h3;
            suf[b0 + 1] = tail + h3 + h2;
            suf[b0 + 0] = tail + h3 + h2 + h1;
        }
        __syncthreads();
        {
            int sb = (int)suf[tid];
            if (sb < need && sb + (int)hist[tid] >= need) {
                scal[0] = (unsigned)tid;
                scal[1] = (unsigned)(need - sb);
            }
        }
        __syncthreads();
        unsigned Bb = scal[0];
        need = (int)scal[1];
        thresh = (thresh << 8) | Bb;
        #pragma unroll
        for (int j = 0; j < 8; ++j)
            if ((actmask >> j) & 1u)
                if (((key[j] >> shift) & 0xffu) != Bb) actmask &= ~(1u << j);
        __syncthreads();
    }
    if (tid == 0) { scal[2] = 0; scal[3] = 0; }
    __syncthreads();
    int* op = Mtop + bh * UU;
    #pragma unroll
    for (int j = 0; j < 8; ++j) {
        if (key[j] > thresh) {
            unsigned p = atomicAdd(&scal[2], 1u);
            op[p] = base + j;
        } else if (key[j] == thresh) {
            unsigned p = atomicAdd(&scal[3], 1u);
            if (p < 64) eq_list[p] = base + j;
        }
    }
    __syncthreads();
    unsigned cnt = scal[2], eqc = scal[3];
    if ((int)eqc == need) {
        if (tid < (unsigned)need) op[cnt + tid] = eq_list[tid];
    } else if (tid == 0) {
        if (eqc <= 64u) {
            for (int t = 0; t < need; ++t) {
                int mi = t;
                for (int j = t + 1; j < (int)eqc; ++j)
                    if (eq_list[j] < eq_list[mi]) mi = j;
                int tmp = eq_list[t]; eq_list[t] = eq_list[mi]; eq_list[mi] = tmp;
                op[cnt + t] = eq_list[t];
            }
        } else {
            int taken = 0;
            for (int i = 0; i < L_SEQ && taken < need; ++i) {
                unsigned u = __float_as_uint(Mrow[i]);
                unsigned k = (u & 0x80000000u) ? ~u : (u | 0x80000000u);
                if (k == thresh) op[cnt + taken++] = i;
            }
        }
    }
    __syncthreads();
}

// exclusive prefix over 256 chunk-sums per (bh,d); buf = 8192 floats (32KB), two passes
__device__ void prefix_body(float* __restrict__ cs8, int bh, int tid, float* buf) {
    float* g = cs8 + (size_t)bh * 16384;
    float run = 0.f;
    for (int half = 0; half < 2; ++half) {
        float* gh = g + half * 8192;
        for (int it = 0; it < 8; ++it) {
            int i = it * 1024 + tid * 4;
            *(float4*)&buf[i] = *(const float4*)&gh[i];
        }
        __syncthreads();
        if (tid < 64) {
            for (int c = 0; c < 128; ++c) {
                float t = buf[c * 64 + tid];
                buf[c * 64 + tid] = run;
                run += t;
            }
        }
        __syncthreads();
        for (int it = 0; it < 8; ++it) {
            int i = it * 1024 + tid * 4;
            *(float4*)&gh[i] = *(const float4*)&buf[i];
        }
        __syncthreads();
    }
}

// attention over key-splits (online softmax within block); smem pointers supplied
__device__ void attn_body(const float* __restrict__ Qg, const float* __restrict__ Kg,
                          const float* __restrict__ Vg, const int* __restrict__ Mtop,
                          float* __restrict__ pm, float* __restrict__ pl,
                          float* __restrict__ pO, float* __restrict__ out,
                          int nsplit, int direct, int bx, int tid,
                          float* qs, float* ks, float* ps,
                          float* mm, float* ll, float* al) {
    int bh = bx / nsplit, sp = bx - bh * nsplit;
    int b = bh >> 3, h = bh & 7;
    int cpb = 32 / nsplit;
    const int* mt = Mtop + bh * UU;

    for (int i = tid; i < UU * DIM / 8; i += 256) {
        int u = i >> 3, dv = (i & 7) * 8;
        int row = mt[u];
        const float* qp = Qg + ((size_t)(b * L_SEQ + row) * NH + h) * DIM + dv;
        *(float4*)&qs[u * DIM + dv]     = *(const float4*)qp;
        *(float4*)&qs[u * DIM + dv + 4] = *(const float4*)(qp + 4);
    }
    if (tid < UU) { mm[tid] = -INFINITY; ll[tid] = 0.f; }

    int d0 = (tid & 31) * 2, ugp = tid >> 5;
    float o0[5], o1[5];
    #pragma unroll
    for (int j = 0; j < 5; ++j) { o0[j] = 0.f; o1[j] = 0.f; }

    for (int c = 0; c < cpb; ++c) {
        int k0 = (sp * cpb + c) * 64;
        if (c) __syncthreads();
        for (int i = tid; i < 64 * DIM / 8; i += 256) {
            int r = i >> 3, dv = (i & 7) * 8;
            const float* kp = Kg + ((size_t)(b * L_SEQ + k0 + r) * NH + h) * DIM + dv;
            *(float4*)&ks[r * 68 + dv]     = *(const float4*)kp;
            *(float4*)&ks[r * 68 + dv + 4] = *(const float4*)(kp + 4);
        }
        __syncthreads();
        {
            int k = tid & 63, ug = tid >> 6;
            float acc[10];
            #pragma unroll
            for (int j = 0; j < 10; ++j) acc[j] = 0.f;
            for (int d = 0; d < DIM; d += 4) {
                float4 kv = *(float4*)&ks[k * 68 + d];
                #pragma unroll
                for (int j = 0; j < 10; ++j) {
                    float4 qv = *(float4*)&qs[(ug * 10 + j) * DIM + d];
                    acc[j] = fmaf(qv.x, kv.x, acc[j]);
                    acc[j] = fmaf(qv.y, kv.y, acc[j]);
                    acc[j] = fmaf(qv.z, kv.z, acc[j]);
                    acc[j] = fmaf(qv.w, kv.w, acc[j]);
                }
            }
            #pragma unroll
            for (int j = 0; j < 10; ++j) ps[(ug * 10 + j) * 68 + k] = acc[j] * 0.125f;
        }
        __syncthreads();
        for (int i = tid; i < 64 * DIM / 8; i += 256) {
            int r = i >> 3, dv = (i & 7) * 8;
            const float* vp = Vg + ((size_t)(b * L_SEQ + k0 + r) * NH + h) * DIM + dv;
            *(float4*)&ks[r * 68 + dv]     = *(const float4*)vp;
            *(float4*)&ks[r * 68 + dv + 4] = *(const float4*)(vp + 4);
        }
        if (tid < UU) {
            float mc = -INFINITY;
            for (int k = 0; k < 64; ++k) mc = fmaxf(mc, ps[tid * 68 + k]);
            float mn = fmaxf(mm[tid], mc);
            float a = __expf(mm[tid] - mn);
            float s = 0.f;
            for (int k = 0; k < 64; ++k) {
                float e = __expf(ps[tid * 68 + k] - mn);
                ps[tid * 68 + k] = e;
                s += e;
            }
            ll[tid] = ll[tid] * a + s;
            mm[tid] = mn;
            al[tid] = a;
        }
        __syncthreads();
        {
            #pragma unroll
            for (int j = 0; j < 5; ++j) {
                float a = al[ugp * 5 + j];
                o0[j] *= a; o1[j] *= a;
            }
            for (int k = 0; k < 64; k += 4) {
                float vf0[4], vf1[4];
                #pragma unroll
                for (int kk = 0; kk < 4; ++kk) {
                    float2 vv = *(float2*)&ks[(k + kk) * 68 + d0];
                    vf0[kk] = vv.x;
                    vf1[kk] = vv.y;
                }
                #pragma unroll
                for (int j = 0; j < 5; ++j) {
                    float4 pv = *(float4*)&ps[(ugp * 5 + j) * 68 + k];
                    o0[j] = fmaf(pv.x, vf0[0], o0[j]); o1[j] = fmaf(pv.x, vf1[0], o1[j]);
                    o0[j] = fmaf(pv.y, vf0[1], o0[j]); o1[j] = fmaf(pv.y, vf1[1], o1[j]);
                    o0[j] = fmaf(pv.z, vf0[2], o0[j]); o1[j] = fmaf(pv.z, vf1[2], o1[j]);
                    o0[j] = fmaf(pv.w, vf0[3], o0[j]); o1[j] = fmaf(pv.w, vf1[3], o1[j]);
                }
            }
        }
    }

    if (!direct) {
        if (tid < UU) {
            pm[((size_t)bh * nsplit + sp) * UU + tid] = mm[tid];
            pl[((size_t)bh * nsplit + sp) * UU + tid] = ll[tid];
        }
        size_t basep = ((size_t)bh * nsplit + sp) * UU * DIM;
        #pragma unroll
        for (int j = 0; j < 5; ++j) {
            *(float2*)&pO[basep + (size_t)(ugp * 5 + j) * DIM + d0] = make_float2(o0[j], o1[j]);
        }
    } else {
        #pragma unroll
        for (int j = 0; j < 5; ++j) {
            int u = ugp * 5 + j;
            int row = mt[u];
            float inv = 1.0f / ll[u];
            size_t o = ((size_t)(b * L_SEQ + row) * NH + h) * DIM + d0;
            out[o]     = o0[j] * inv;
            out[o + 1] = o1[j] * inv;
        }
    }
}

__device__ __forceinline__ void combine_body(const float* __restrict__ pm,
                                             const float* __restrict__ pl,
                                             const float* __restrict__ pO,
                                             const int* __restrict__ Mtop,
                                             float* __restrict__ out, int nsplit,
                                             int wid, int lane) {
    int u = wid % UU;
    int bh = wid / UU;
    int b = bh >> 3, h = bh & 7;
    float mg = -INFINITY;
    for (int c = 0; c < nsplit; ++c) mg = fmaxf(mg, pm[((size_t)bh * nsplit + c) * UU + u]);
    float acc = 0.f, lsum = 0.f;
    for (int c = 0; c < nsplit; ++c) {
        size_t pb = ((size_t)bh * nsplit + c) * UU + u;
        float w = __expf(pm[pb] - mg);
        lsum = fmaf(pl[pb], w, lsum);
        acc = fmaf(w, pO[pb * DIM + lane], acc);
    }
    int row = Mtop[bh * UU + u];
    out[((size_t)(b * L_SEQ + row) * NH + h) * DIM + lane] = acc / lsum;
}

// ======================= cooperative mono-kernel =======================
// 1024 blocks x 256 thr, 4 blocks/CU co-resident (39KB LDS, VGPR<=128).
#define NSPLIT 8
__global__ __launch_bounds__(256, 4) void mono_kernel(
    const float* __restrict__ Qg, const float* __restrict__ Kg,
    const float* __restrict__ Vg, const int* __restrict__ idx,
    float* __restrict__ M, int* __restrict__ Mtop,
    float* __restrict__ pm, float* __restrict__ pl, float* __restrict__ pO,
    float* __restrict__ cs8, float* __restrict__ out) {
    __shared__ float smem[9752];   // 39008 B union: attn | topk | prefix
    cg::grid_group grid = cg::this_grid();
    int bx = blockIdx.x, tid = threadIdx.x;

    // P1: m (virtual 0..2047) || csum8 (2048..4095)
    #pragma unroll
    for (int i = 0; i < 4; ++i) {
        int v = bx + 1024 * i;
        if (v < 2048) {
            m_body(Qg, Kg, idx, M, v, tid);
        } else {
            int wid = (v - 2048) * 4 + (tid >> 6);
            csum8_body(Vg, cs8, wid, tid & 63);
        }
    }
    grid.sync();

    // P2: topk (32 blocks) || prefix (32 blocks)
    if (bx < 32) topk_body(M, Mtop, bx, tid, smem);
    else if (bx < 64) prefix_body(cs8, bx - 32, tid, smem);
    grid.sync();

    // P3: attn partials (256 blocks) || cumsum write (768 blocks x up to 3)
    if (bx < 32 * NSPLIT) {
        attn_body(Qg, Kg, Vg, Mtop, pm, pl, pO, out, NSPLIT, 0, bx, tid,
                  smem, smem + 2560, smem + 6912,
                  smem + 9632, smem + 9672, smem + 9712);
    } else {
        #pragma unroll
        for (int i = 0; i < 3; ++i) {
            int v = (bx - 256) + 768 * i;
            if (v < 2048) {
                int wid = v * 4 + (tid >> 6);
                write8_body(Vg, cs8, out, wid, tid & 63);
            }
        }
    }
    grid.sync();

    // P4: combine + scatter (320 blocks)
    if (bx < 320) {
        int wid = bx * 4 + (tid >> 6);
        combine_body(pm, pl, pO, Mtop, out, NSPLIT, wid, tid & 63);
    }
}

// ======================= fallback (R6-style 4-kernel path) =======================

__global__ __launch_bounds__(256) void stage1_kernel(const float* __restrict__ Qg,
                                                     const float* __restrict__ Kg,
                                                     const int* __restrict__ idx,
                                                     const float* __restrict__ Vg,
                                                     float* __restrict__ M,
                                                     float* __restrict__ cs8) {
    int bx = blockIdx.x, tid = threadIdx.x;
    if (bx < 2048) {
        m_body(Qg, Kg, idx, M, bx, tid);
    } else {
        int wid = (bx - 2048) * 4 + (tid >> 6);
        csum8_body(Vg, cs8, wid, tid & 63);
    }
}

__global__ __launch_bounds__(256) void stage2_kernel(const float* __restrict__ M,
                                                     int* __restrict__ Mtop,
                                                     float* __restrict__ cs8) {
    __shared__ float sbuf[8192];
    int bx = blockIdx.x, tid = threadIdx.x;
    if (bx < 32) topk_body(M, Mtop, bx, tid, sbuf);
    else prefix_body(cs8, bx - 32, tid, sbuf);
}

__global__ __launch_bounds__(256) void stage3_kernel(const float* __restrict__ Qg,
                                                     const float* __restrict__ Kg,
                                                     const float* __restrict__ Vg,
                                                     const int* __restrict__ Mtop,
                                                     const float* __restrict__ cs8,
                                                     float* __restrict__ pm,
                                                     float* __restrict__ pl,
                                                     float* __restrict__ pO,
                                                     float* __restrict__ out,
                                                     int nattn, int nsplit) {
    __shared__ float smem[9752];
    int bx = blockIdx.x, tid = threadIdx.x;
    if (bx < nattn) {
        attn_body(Qg, Kg, Vg, Mtop, pm, pl, pO, out, nsplit, 0, bx, tid,
                  smem, smem + 2560, smem + 6912,
                  smem + 9632, smem + 9672, smem + 9712);
    } else {
        int wid = (bx - nattn) * 4 + (tid >> 6);
        write8_body(Vg, cs8, out, wid, tid & 63);
    }
}

__global__ __launch_bounds__(256) void attn_kernel(const float* __restrict__ Qg,
                                                   const float* __restrict__ Kg,
                                                   const float* __restrict__ Vg,
                                                   const int* __restrict__ Mtop,
                                                   float* __restrict__ out) {
    __shared__ float smem[9752];
    attn_body(Qg, Kg, Vg, Mtop, nullptr, nullptr, nullptr, out, 1, 1,
              blockIdx.x, threadIdx.x,
              smem, smem + 2560, smem + 6912,
              smem + 9632, smem + 9672, smem + 9712);
}

__global__ __launch_bounds__(256) void combine_kernel(const float* __restrict__ pm,
                                                      const float* __restrict__ pl,
                                                      const float* __restrict__ pO,
                                                      const int* __restrict__ Mtop,
                                                      float* __restrict__ out, int nsplit) {
    int wid = blockIdx.x * 4 + (threadIdx.x >> 6);
    combine_body(pm, pl, pO, Mtop, out, nsplit, wid, threadIdx.x & 63);
}

// fused cumsum fallback (ultra-slim ws)
__global__ __launch_bounds__(256) void csum_fused_kernel(const float* __restrict__ Vg,
                                                         float* __restrict__ out) {
    __shared__ float css[32 * 64];
    int bh = blockIdx.x, tid = threadIdx.x;
    int b = bh >> 3, h = bh & 7;
    int cc = tid >> 3, d8 = (tid & 7) * 8;
    size_t off = ((size_t)(b * L_SEQ + cc * 64) * NH + h) * DIM + d8;
    const float* Vp = Vg + off;
    float s[8];
    #pragma unroll
    for (int j = 0; j < 8; ++j) s[j] = 0.f;
    for (int l = 0; l < 64; ++l) {
        float4 r0 = *(const float4*)(Vp + (size_t)l * NHD);
        float4 r1 = *(const float4*)(Vp + (size_t)l * NHD + 4);
        s[0] += r0.x; s[1] += r0.y; s[2] += r0.z; s[3] += r0.w;
        s[4] += r1.x; s[5] += r1.y; s[6] += r1.z; s[7] += r1.w;
    }
    #pragma unroll
    for (int j = 0; j < 8; ++j) css[cc * 64 + d8 + j] = s[j];
    __syncthreads();
    if (tid < 64) {
        float run = 0.f;
        for (int c = 0; c < 32; ++c) {
            float t = css[c * 64 + tid];
            css[c * 64 + tid] = run;
            run += t;
        }
    }
    __syncthreads();
    float r8[8];
    #pragma unroll
    for (int j = 0; j < 8; ++j) r8[j] = css[cc * 64 + d8 + j];
    float* Op = out + off;
    for (int l = 0; l < 64; ++l) {
        float4 r0 = *(const float4*)(Vp + (size_t)l * NHD);
        float4 r1 = *(const float4*)(Vp + (size_t)l * NHD + 4);
        r8[0] += r0.x; r8[1] += r0.y; r8[2] += r0.z; r8[3] += r0.w;
        r8[4] += r1.x; r8[5] += r1.y; r8[6] += r1.z; r8[7] += r1.w;
        *(float4*)(Op + (size_t)l * NHD)     = make_float4(r8[0], r8[1], r8[2], r8[3]);
        *(float4*)(Op + (size_t)l * NHD + 4) = make_float4(r8[4], r8[5], r8[6], r8[7]);
    }
}

extern "C" void kernel_launch(void* const* d_in, const int* in_sizes, int n_in,
                              void* d_out, int out_size, void* d_ws, size_t ws_size,
                              hipStream_t stream) {
    const float* Q = (const float*)d_in[0];
    const float* K = (const float*)d_in[1];
    const float* V = (const float*)d_in[2];
    const int* idx = (const int*)d_in[3];
    float* out = (float*)d_out;
    float* wsf = (float*)d_ws;

    const int n = NSPLIT;
    // ws floats: M[65536] | Mtop[1280 int] | pm[10240] | pl[10240] | pO[655360] | cs8[524288]
    size_t need_full = (size_t)(65536 + 1280 + 1280 * n * 2 + 81920 * n + 524288) * 4;

    if (ws_size >= need_full) {
        float* M    = wsf;
        int*   Mtop = (int*)(wsf + 65536);
        float* pm   = wsf + 66816;
        float* pl   = pm + 1280 * (size_t)n;
        float* pO   = pl + 1280 * (size_t)n;
        float* cs8  = pO + 81920 * (size_t)n;

        int coop = 0, dev = 0;
        hipGetDevice(&dev);
        hipDeviceGetAttribute(&coop, hipDeviceAttributeCooperativeLaunch, dev);
        hipError_t e = hipErrorUnknown;
        if (coop) {
            void* args[] = {(void*)&Q, (void*)&K, (void*)&V, (void*)&idx,
                            (void*)&M, (void*)&Mtop, (void*)&pm, (void*)&pl,
                            (void*)&pO, (void*)&cs8, (void*)&out};
            e = hipLaunchCooperativeKernel((void*)mono_kernel, dim3(1024), dim3(256),
                                           args, 0, stream);
        }
        if (e != hipSuccess) {
            // fallback: 4-kernel path (proven)
            stage1_kernel<<<4096, 256, 0, stream>>>(Q, K, idx, V, M, cs8);
            stage2_kernel<<<64, 256, 0, stream>>>(M, Mtop, cs8);
            stage3_kernel<<<32 * n + 2048, 256, 0, stream>>>(Q, K, V, Mtop, cs8,
                                                             pm, pl, pO, out, 32 * n, n);
            combine_kernel<<<320, 256, 0, stream>>>(pm, pl, pO, Mtop, out, n);
        }
    } else {
        // ultra-slim: M staged in d_out (overwritten later), Mtop in ws
        float* M    = (float*)d_out;
        int*   Mtop = (int*)d_ws;
        stage1_kernel<<<2048, 256, 0, stream>>>(Q, K, idx, nullptr, M, nullptr);
        stage2_kernel<<<32, 256, 0, stream>>>(M, Mtop, nullptr);
        csum_fused_kernel<<<32, 256, 0, stream>>>(V, out);
        attn_kernel<<<32, 256, 0, stream>>>(Q, K, V, Mtop, out);
    }
}

// Round 9
// 166.789 us; speedup vs baseline: 3.3009x; 3.3009x over previous
//
#include <hip/hip_runtime.h>

#define L_SEQ 2048
#define NH 8
#define DIM 64
#define SS 40
#define UU 40
#define NHD 512   // NH*DIM floats between consecutive l rows

// ======================= device bodies =======================

// m-score v3: 2 waves per (b,l); wave covers 4 heads. lane = hp*16 + c.
// Per sample the wave reads a contiguous 1KB half-row (1 float4/lane) ->
// 10 samples in flight (40 data VGPRs), L2-BW bound instead of latency bound.
__device__ __forceinline__ void m_body(const float* __restrict__ Qg,
                                       const float* __restrict__ Kg,
                                       const int* __restrict__ idx,
                                       float* __restrict__ M,
                                       int bx, int tid) {
    int w = tid >> 6, lane = tid & 63;
    int b = bx & 3;                         // XCD-pinned
    int l = (bx >> 2) * 2 + (w >> 1);
    int half = w & 1;
    int hp = lane >> 4;
    int h = half * 4 + hp;
    int c = lane & 15;                      // 16 lanes x float4 = 64 floats per head

    const float* Qp = Qg + ((size_t)(b * L_SEQ + l) * NH + h) * DIM + c * 4;
    float4 q = *(const float4*)Qp;
    const float* Kbase = Kg + (size_t)b * L_SEQ * NHD + h * DIM + c * 4;
    const int* ip = idx + l * SS;           // wave-uniform -> scalar loads

    float mx = -INFINITY, sm = 0.f;
    #pragma unroll
    for (int s0 = 0; s0 < SS; s0 += 10) {
        float4 kd[10];
        #pragma unroll
        for (int j = 0; j < 10; ++j)
            kd[j] = *(const float4*)(Kbase + (size_t)ip[s0 + j] * NHD);
        #pragma unroll
        for (int j = 0; j < 10; ++j) {
            float d_ = kd[j].x * q.x;
            d_ = fmaf(kd[j].y, q.y, d_);
            d_ = fmaf(kd[j].z, q.z, d_);
            d_ = fmaf(kd[j].w, q.w, d_);
            d_ += __shfl_xor(d_, 1);
            d_ += __shfl_xor(d_, 2);
            d_ += __shfl_xor(d_, 4);
            d_ += __shfl_xor(d_, 8);
            mx = fmaxf(mx, d_);
            sm += d_;
        }
    }
    if (c == 0) M[((size_t)(b * NH + h)) * L_SEQ + l] = mx - sm * (1.0f / (float)L_SEQ);
}

__device__ __forceinline__ void csum8_body(const float* __restrict__ Vg,
                                           float* __restrict__ cs8,
                                           int wid, int lane) {
    int c8 = wid & 255, bh = wid >> 8;
    int b = bh >> 3, h = bh & 7;
    const float* Vp = Vg + ((size_t)(b * L_SEQ + c8 * 8) * NH + h) * DIM + lane;
    float s = 0.f;
    #pragma unroll
    for (int j = 0; j < 8; ++j) s += Vp[(size_t)j * NHD];
    cs8[((size_t)bh * 256 + c8) * 64 + lane] = s;
}

__device__ __forceinline__ void write8_body(const float* __restrict__ Vg,
                                            const float* __restrict__ cs8,
                                            float* __restrict__ out,
                                            int wid, int lane) {
    int c8 = wid & 255, bh = wid >> 8;
    int b = bh >> 3, h = bh & 7;
    float run = cs8[((size_t)bh * 256 + c8) * 64 + lane];
    size_t off = ((size_t)(b * L_SEQ + c8 * 8) * NH + h) * DIM + lane;
    const float* Vp = Vg + off;
    float* Op = out + off;
    #pragma unroll
    for (int j = 0; j < 8; ++j) {
        run += Vp[(size_t)j * NHD];
        Op[(size_t)j * NHD] = run;
    }
}

// top-40 per bh via 4-round radix select; smemf provides >=580 floats
__device__ void topk_body(const float* __restrict__ M, int* __restrict__ Mtop,
                          int bh, int tid, float* smemf) {
    unsigned* hist = (unsigned*)smemf;
    unsigned* suf  = hist + 256;
    int* eq_list   = (int*)(suf + 256);
    unsigned* scal = (unsigned*)(eq_list + 64);
    const float* Mrow = M + (size_t)bh * L_SEQ;
    int base = tid * 8;

    float4 a0 = *(const float4*)(Mrow + base);
    float4 a1 = *(const float4*)(Mrow + base + 4);
    float fv[8] = {a0.x, a0.y, a0.z, a0.w, a1.x, a1.y, a1.z, a1.w};
    unsigned key[8];
    #pragma unroll
    for (int j = 0; j < 8; ++j) {
        unsigned u = __float_as_uint(fv[j]);
        key[j] = (u & 0x80000000u) ? ~u : (u | 0x80000000u);
    }
    unsigned actmask = 0xffu, thresh = 0;
    int need = UU;
    #pragma unroll
    for (int shift = 24; shift >= 0; shift -= 8) {
        hist[tid] = 0;
        __syncthreads();
        #pragma unroll
        for (int j = 0; j < 8; ++j)
            if ((actmask >> j) & 1u)
                atomicAdd(&hist[(key[j] >> shift) & 0xffu], 1u);
        __syncthreads();
        if (tid < 64) {
            int b0 = tid * 4;
            unsigned h0 = hist[b0], h1 = hist[b0 + 1], h2 = hist[b0 + 2], h3 = hist[b0 + 3];
            unsigned loc = h0 + h1 + h2 + h3;
            unsigned s = loc;
            #pragma unroll
            for (int off = 1; off < 64; off <<= 1) {
                unsigned o = __shfl_down(s, off, 64);
                if (tid + off < 64) s += o;
            }
            unsigned tail = s - loc;
            suf[b0 + 3] = tail;
            suf[b0 + 2] = tail + h3;
            suf[b0 + 1] = tail + h3 + h2;
            suf[b0 + 0] = tail + h3 + h2 + h1;
        }
        __syncthreads();
        {
            int sb = (int)suf[tid];
            if (sb < need && sb + (int)hist[tid] >= need) {
                scal[0] = (unsigned)tid;
                scal[1] = (unsigned)(need - sb);
            }
        }
        __syncthreads();
        unsigned Bb = scal[0];
        need = (int)scal[1];
        thresh = (thresh << 8) | Bb;
        #pragma unroll
        for (int j = 0; j < 8; ++j)
            if ((actmask >> j) & 1u)
                if (((key[j] >> shift) & 0xffu) != Bb) actmask &= ~(1u << j);
        __syncthreads();
    }
    if (tid == 0) { scal[2] = 0; scal[3] = 0; }
    __syncthreads();
    int* op = Mtop + bh * UU;
    #pragma unroll
    for (int j = 0; j < 8; ++j) {
        if (key[j] > thresh) {
            unsigned p = atomicAdd(&scal[2], 1u);
            op[p] = base + j;
        } else if (key[j] == thresh) {
            unsigned p = atomicAdd(&scal[3], 1u);
            if (p < 64) eq_list[p] = base + j;
        }
    }
    __syncthreads();
    unsigned cnt = scal[2], eqc = scal[3];
    if ((int)eqc == need) {
        if (tid < (unsigned)need) op[cnt + tid] = eq_list[tid];
    } else if (tid == 0) {
        if (eqc <= 64u) {
            for (int t = 0; t < need; ++t) {
                int mi = t;
                for (int j = t + 1; j < (int)eqc; ++j)
                    if (eq_list[j] < eq_list[mi]) mi = j;
                int tmp = eq_list[t]; eq_list[t] = eq_list[mi]; eq_list[mi] = tmp;
                op[cnt + t] = eq_list[t];
            }
        } else {
            int taken = 0;
            for (int i = 0; i < L_SEQ && taken < need; ++i) {
                unsigned u = __float_as_uint(Mrow[i]);
                unsigned k = (u & 0x80000000u) ? ~u : (u | 0x80000000u);
                if (k == thresh) op[cnt + taken++] = i;
            }
        }
    }
    __syncthreads();
}

// exclusive prefix over 256 chunk-sums per (bh,d); buf = 8192 floats, two passes
__device__ void prefix_body(float* __restrict__ cs8, int bh, int tid, float* buf) {
    float* g = cs8 + (size_t)bh * 16384;
    float run = 0.f;
    for (int half = 0; half < 2; ++half) {
        float* gh = g + half * 8192;
        for (int it = 0; it < 8; ++it) {
            int i = it * 1024 + tid * 4;
            *(float4*)&buf[i] = *(const float4*)&gh[i];
        }
        __syncthreads();
        if (tid < 64) {
            for (int c = 0; c < 128; ++c) {
                float t = buf[c * 64 + tid];
                buf[c * 64 + tid] = run;
                run += t;
            }
        }
        __syncthreads();
        for (int it = 0; it < 8; ++it) {
            int i = it * 1024 + tid * 4;
            *(float4*)&gh[i] = *(const float4*)&buf[i];
        }
        __syncthreads();
    }
}

// attention over key-splits (online softmax within block)
__device__ void attn_body(const float* __restrict__ Qg, const float* __restrict__ Kg,
                          const float* __restrict__ Vg, const int* __restrict__ Mtop,
                          float* __restrict__ pm, float* __restrict__ pl,
                          float* __restrict__ pO, float* __restrict__ out,
                          int nsplit, int direct, int bx, int tid,
                          float* qs, float* ks, float* ps,
                          float* mm, float* ll, float* al) {
    int bh = bx / nsplit, sp = bx - bh * nsplit;
    int b = bh >> 3, h = bh & 7;
    int cpb = 32 / nsplit;
    const int* mt = Mtop + bh * UU;

    for (int i = tid; i < UU * DIM / 8; i += 256) {
        int u = i >> 3, dv = (i & 7) * 8;
        int row = mt[u];
        const float* qp = Qg + ((size_t)(b * L_SEQ + row) * NH + h) * DIM + dv;
        *(float4*)&qs[u * DIM + dv]     = *(const float4*)qp;
        *(float4*)&qs[u * DIM + dv + 4] = *(const float4*)(qp + 4);
    }
    if (tid < UU) { mm[tid] = -INFINITY; ll[tid] = 0.f; }

    int d0 = (tid & 31) * 2, ugp = tid >> 5;
    float o0[5], o1[5];
    #pragma unroll
    for (int j = 0; j < 5; ++j) { o0[j] = 0.f; o1[j] = 0.f; }

    for (int c = 0; c < cpb; ++c) {
        int k0 = (sp * cpb + c) * 64;
        if (c) __syncthreads();
        for (int i = tid; i < 64 * DIM / 8; i += 256) {
            int r = i >> 3, dv = (i & 7) * 8;
            const float* kp = Kg + ((size_t)(b * L_SEQ + k0 + r) * NH + h) * DIM + dv;
            *(float4*)&ks[r * 68 + dv]     = *(const float4*)kp;
            *(float4*)&ks[r * 68 + dv + 4] = *(const float4*)(kp + 4);
        }
        __syncthreads();
        {
            int k = tid & 63, ug = tid >> 6;
            float acc[10];
            #pragma unroll
            for (int j = 0; j < 10; ++j) acc[j] = 0.f;
            for (int d = 0; d < DIM; d += 4) {
                float4 kv = *(float4*)&ks[k * 68 + d];
                #pragma unroll
                for (int j = 0; j < 10; ++j) {
                    float4 qv = *(float4*)&qs[(ug * 10 + j) * DIM + d];
                    acc[j] = fmaf(qv.x, kv.x, acc[j]);
                    acc[j] = fmaf(qv.y, kv.y, acc[j]);
                    acc[j] = fmaf(qv.z, kv.z, acc[j]);
                    acc[j] = fmaf(qv.w, kv.w, acc[j]);
                }
            }
            #pragma unroll
            for (int j = 0; j < 10; ++j) ps[(ug * 10 + j) * 68 + k] = acc[j] * 0.125f;
        }
        __syncthreads();
        for (int i = tid; i < 64 * DIM / 8; i += 256) {
            int r = i >> 3, dv = (i & 7) * 8;
            const float* vp = Vg + ((size_t)(b * L_SEQ + k0 + r) * NH + h) * DIM + dv;
            *(float4*)&ks[r * 68 + dv]     = *(const float4*)vp;
            *(float4*)&ks[r * 68 + dv + 4] = *(const float4*)(vp + 4);
        }
        if (tid < UU) {
            float mc = -INFINITY;
            for (int k = 0; k < 64; ++k) mc = fmaxf(mc, ps[tid * 68 + k]);
            float mn = fmaxf(mm[tid], mc);
            float a = __expf(mm[tid] - mn);
            float s = 0.f;
            for (int k = 0; k < 64; ++k) {
                float e = __expf(ps[tid * 68 + k] - mn);
                ps[tid * 68 + k] = e;
                s += e;
            }
            ll[tid] = ll[tid] * a + s;
            mm[tid] = mn;
            al[tid] = a;
        }
        __syncthreads();
        {
            #pragma unroll
            for (int j = 0; j < 5; ++j) {
                float a = al[ugp * 5 + j];
                o0[j] *= a; o1[j] *= a;
            }
            for (int k = 0; k < 64; k += 4) {
                float vf0[4], vf1[4];
                #pragma unroll
                for (int kk = 0; kk < 4; ++kk) {
                    float2 vv = *(float2*)&ks[(k + kk) * 68 + d0];
                    vf0[kk] = vv.x;
                    vf1[kk] = vv.y;
                }
                #pragma unroll
                for (int j = 0; j < 5; ++j) {
                    float4 pv = *(float4*)&ps[(ugp * 5 + j) * 68 + k];
                    o0[j] = fmaf(pv.x, vf0[0], o0[j]); o1[j] = fmaf(pv.x, vf1[0], o1[j]);
                    o0[j] = fmaf(pv.y, vf0[1], o0[j]); o1[j] = fmaf(pv.y, vf1[1], o1[j]);
                    o0[j] = fmaf(pv.z, vf0[2], o0[j]); o1[j] = fmaf(pv.z, vf1[2], o1[j]);
                    o0[j] = fmaf(pv.w, vf0[3], o0[j]); o1[j] = fmaf(pv.w, vf1[3], o1[j]);
                }
            }
        }
    }

    if (!direct) {
        if (tid < UU) {
            pm[((size_t)bh * nsplit + sp) * UU + tid] = mm[tid];
            pl[((size_t)bh * nsplit + sp) * UU + tid] = ll[tid];
        }
        size_t basep = ((size_t)bh * nsplit + sp) * UU * DIM;
        #pragma unroll
        for (int j = 0; j < 5; ++j) {
            *(float2*)&pO[basep + (size_t)(ugp * 5 + j) * DIM + d0] = make_float2(o0[j], o1[j]);
        }
    } else {
        #pragma unroll
        for (int j = 0; j < 5; ++j) {
            int u = ugp * 5 + j;
            int row = mt[u];
            float inv = 1.0f / ll[u];
            size_t o = ((size_t)(b * L_SEQ + row) * NH + h) * DIM + d0;
            out[o]     = o0[j] * inv;
            out[o + 1] = o1[j] * inv;
        }
    }
}

__device__ __forceinline__ void combine_body(const float* __restrict__ pm,
                                             const float* __restrict__ pl,
                                             const float* __restrict__ pO,
                                             const int* __restrict__ Mtop,
                                             float* __restrict__ out, int nsplit,
                                             int wid, int lane) {
    int u = wid % UU;
    int bh = wid / UU;
    int b = bh >> 3, h = bh & 7;
    float mg = -INFINITY;
    for (int c = 0; c < nsplit; ++c) mg = fmaxf(mg, pm[((size_t)bh * nsplit + c) * UU + u]);
    float acc = 0.f, lsum = 0.f;
    for (int c = 0; c < nsplit; ++c) {
        size_t pb = ((size_t)bh * nsplit + c) * UU + u;
        float w = __expf(pm[pb] - mg);
        lsum = fmaf(pl[pb], w, lsum);
        acc = fmaf(w, pO[pb * DIM + lane], acc);
    }
    int row = Mtop[bh * UU + u];
    out[((size_t)(b * L_SEQ + row) * NH + h) * DIM + lane] = acc / lsum;
}

// ======================= stage kernels (4-launch path) =======================

// stage1: blocks [0,4096) m-score v3 (2 l's x 2 waves each) ; [4096,6144) csum8
__global__ __launch_bounds__(256) void stage1_kernel(const float* __restrict__ Qg,
                                                     const float* __restrict__ Kg,
                                                     const int* __restrict__ idx,
                                                     const float* __restrict__ Vg,
                                                     float* __restrict__ M,
                                                     float* __restrict__ cs8) {
    int bx = blockIdx.x, tid = threadIdx.x;
    if (bx < 4096) {
        m_body(Qg, Kg, idx, M, bx, tid);
    } else {
        int wid = (bx - 4096) * 4 + (tid >> 6);
        csum8_body(Vg, cs8, wid, tid & 63);
    }
}

__global__ __launch_bounds__(256) void stage2_kernel(const float* __restrict__ M,
                                                     int* __restrict__ Mtop,
                                                     float* __restrict__ cs8) {
    __shared__ float sbuf[8192];
    int bx = blockIdx.x, tid = threadIdx.x;
    if (bx < 32) topk_body(M, Mtop, bx, tid, sbuf);
    else prefix_body(cs8, bx - 32, tid, sbuf);
}

__global__ __launch_bounds__(256) void stage3_kernel(const float* __restrict__ Qg,
                                                     const float* __restrict__ Kg,
                                                     const float* __restrict__ Vg,
                                                     const int* __restrict__ Mtop,
                                                     const float* __restrict__ cs8,
                                                     float* __restrict__ pm,
                                                     float* __restrict__ pl,
                                                     float* __restrict__ pO,
                                                     float* __restrict__ out,
                                                     int nattn, int nsplit) {
    __shared__ float smem[9752];
    int bx = blockIdx.x, tid = threadIdx.x;
    if (bx < nattn) {
        attn_body(Qg, Kg, Vg, Mtop, pm, pl, pO, out, nsplit, 0, bx, tid,
                  smem, smem + 2560, smem + 6912,
                  smem + 9632, smem + 9672, smem + 9712);
    } else {
        int wid = (bx - nattn) * 4 + (tid >> 6);
        write8_body(Vg, cs8, out, wid, tid & 63);
    }
}

__global__ __launch_bounds__(256) void attn_kernel(const float* __restrict__ Qg,
                                                   const float* __restrict__ Kg,
                                                   const float* __restrict__ Vg,
                                                   const int* __restrict__ Mtop,
                                                   float* __restrict__ out) {
    __shared__ float smem[9752];
    attn_body(Qg, Kg, Vg, Mtop, nullptr, nullptr, nullptr, out, 1, 1,
              blockIdx.x, threadIdx.x,
              smem, smem + 2560, smem + 6912,
              smem + 9632, smem + 9672, smem + 9712);
}

__global__ __launch_bounds__(256) void combine_kernel(const float* __restrict__ pm,
                                                      const float* __restrict__ pl,
                                                      const float* __restrict__ pO,
                                                      const int* __restrict__ Mtop,
                                                      float* __restrict__ out, int nsplit) {
    int wid = blockIdx.x * 4 + (threadIdx.x >> 6);
    combine_body(pm, pl, pO, Mtop, out, nsplit, wid, threadIdx.x & 63);
}

// fused cumsum fallback (ultra-slim ws)
__global__ __launch_bounds__(256) void csum_fused_kernel(const float* __restrict__ Vg,
                                                         float* __restrict__ out) {
    __shared__ float css[32 * 64];
    int bh = blockIdx.x, tid = threadIdx.x;
    int b = bh >> 3, h = bh & 7;
    int cc = tid >> 3, d8 = (tid & 7) * 8;
    size_t off = ((size_t)(b * L_SEQ + cc * 64) * NH + h) * DIM + d8;
    const float* Vp = Vg + off;
    float s[8];
    #pragma unroll
    for (int j = 0; j < 8; ++j) s[j] = 0.f;
    for (int l = 0; l < 64; ++l) {
        float4 r0 = *(const float4*)(Vp + (size_t)l * NHD);
        float4 r1 = *(const float4*)(Vp + (size_t)l * NHD + 4);
        s[0] += r0.x; s[1] += r0.y; s[2] += r0.z; s[3] += r0.w;
        s[4] += r1.x; s[5] += r1.y; s[6] += r1.z; s[7] += r1.w;
    }
    #pragma unroll
    for (int j = 0; j < 8; ++j) css[cc * 64 + d8 + j] = s[j];
    __syncthreads();
    if (tid < 64) {
        float run = 0.f;
        for (int c = 0; c < 32; ++c) {
            float t = css[c * 64 + tid];
            css[c * 64 + tid] = run;
            run += t;
        }
    }
    __syncthreads();
    float r8[8];
    #pragma unroll
    for (int j = 0; j < 8; ++j) r8[j] = css[cc * 64 + d8 + j];
    float* Op = out + off;
    for (int l = 0; l < 64; ++l) {
        float4 r0 = *(const float4*)(Vp + (size_t)l * NHD);
        float4 r1 = *(const float4*)(Vp + (size_t)l * NHD + 4);
        r8[0] += r0.x; r8[1] += r0.y; r8[2] += r0.z; r8[3] += r0.w;
        r8[4] += r1.x; r8[5] += r1.y; r8[6] += r1.z; r8[7] += r1.w;
        *(float4*)(Op + (size_t)l * NHD)     = make_float4(r8[0], r8[1], r8[2], r8[3]);
        *(float4*)(Op + (size_t)l * NHD + 4) = make_float4(r8[4], r8[5], r8[6], r8[7]);
    }
}

extern "C" void kernel_launch(void* const* d_in, const int* in_sizes, int n_in,
                              void* d_out, int out_size, void* d_ws, size_t ws_size,
                              hipStream_t stream) {
    const float* Q = (const float*)d_in[0];
    const float* K = (const float*)d_in[1];
    const float* V = (const float*)d_in[2];
    const int* idx = (const int*)d_in[3];
    float* out = (float*)d_out;
    float* wsf = (float*)d_ws;

    const int n = 8;  // key-splits for attention partials
    // ws floats: M[65536] | Mtop[1280 int] | pm[10240] | pl[10240] | pO[655360] | cs8[524288]
    size_t need_full = (size_t)(65536 + 1280 + 1280 * n * 2 + 81920 * n + 524288) * 4;

    if (ws_size >= need_full) {
        float* M    = wsf;
        int*   Mtop = (int*)(wsf + 65536);
        float* pm   = wsf + 66816;
        float* pl   = pm + 1280 * (size_t)n;
        float* pO   = pl + 1280 * (size_t)n;
        float* cs8  = pO + 81920 * (size_t)n;
        stage1_kernel<<<6144, 256, 0, stream>>>(Q, K, idx, V, M, cs8);
        stage2_kernel<<<64, 256, 0, stream>>>(M, Mtop, cs8);
        stage3_kernel<<<32 * n + 2048, 256, 0, stream>>>(Q, K, V, Mtop, cs8,
                                                         pm, pl, pO, out, 32 * n, n);
        combine_kernel<<<320, 256, 0, stream>>>(pm, pl, pO, Mtop, out, n);
    } else {
        // ultra-slim: M staged in d_out (overwritten later), Mtop in ws
        float* M    = (float*)d_out;
        int*   Mtop = (int*)d_ws;
        stage1_kernel<<<4096, 256, 0, stream>>>(Q, K, idx, nullptr, M, nullptr);
        stage2_kernel<<<32, 256, 0, stream>>>(M, Mtop, nullptr);
        csum_fused_kernel<<<32, 256, 0, stream>>>(V, out);
        attn_kernel<<<32, 256, 0, stream>>>(Q, K, V, Mtop, out);
    }
}